// Round 5
// baseline (361.270 us; speedup 1.0000x reference)
//
#include <hip/hip_runtime.h>
#include <hip/hip_bf16.h>

// Problem constants
#define B_   8
#define LQ   1024
#define LK   8192
#define D_   256
#define DC   128
#define EPSF 1e-6f

typedef __attribute__((ext_vector_type(8))) short short8;   // 8 bf16 (4 VGPRs)
typedef __attribute__((ext_vector_type(4))) float floatx4;  // 4 fp32 acc

static __device__ __forceinline__ floatx4 mfma16(short8 a, short8 b, floatx4 c) {
    return __builtin_amdgcn_mfma_f32_16x16x32_bf16(a, b, c, 0, 0, 0);
}
static __device__ __forceinline__ float fast_rcp(float x)  { return __builtin_amdgcn_rcpf(x); }
static __device__ __forceinline__ float fast_sqrt(float x) { return __builtin_amdgcn_sqrtf(x); }
static __device__ __forceinline__ float fast_ln(float x)   { return 0.69314718056f * __builtin_amdgcn_logf(x); }

// async global->LDS, 16 B per lane; LDS dest = wave-uniform base + lane*16
static __device__ __forceinline__ void gl16(const void* g, void* l) {
    __builtin_amdgcn_global_load_lds(
        (const __attribute__((address_space(1))) unsigned int*)g,
        (__attribute__((address_space(3))) unsigned int*)l, 16, 0, 0);
}

// ---------------------------------------------------------------------------
// K1: G = W_up^T @ W_up (128x128) bf16 + Wt = W^T bf16 (128x256).
// Wt now lives in d_out[0:64KB) — written here, read by k_prep's qproj path,
// overwritten by k_main (stream-ordered; avoids racing the kc buffer now that
// qproj and dq_ksq run concurrently in one launch).
__global__ __launch_bounds__(512) void k_G(const float* __restrict__ W,
                                           __hip_bfloat16* __restrict__ G,
                                           __hip_bfloat16* __restrict__ Wt) {
    __shared__ float red[512];
    int c1 = blockIdx.x;
    int t = threadIdx.x, c2 = t & 127, h = t >> 7;   // h = d-quarter 0..3
    int d0 = h * 64;
    float a0 = 0.f, a1 = 0.f, a2 = 0.f, a3 = 0.f;
#pragma unroll 4
    for (int d = 0; d < 64; d += 4) {
        a0 += W[(size_t)(d0 + d + 0) * DC + c1] * W[(size_t)(d0 + d + 0) * DC + c2];
        a1 += W[(size_t)(d0 + d + 1) * DC + c1] * W[(size_t)(d0 + d + 1) * DC + c2];
        a2 += W[(size_t)(d0 + d + 2) * DC + c1] * W[(size_t)(d0 + d + 2) * DC + c2];
        a3 += W[(size_t)(d0 + d + 3) * DC + c1] * W[(size_t)(d0 + d + 3) * DC + c2];
    }
    red[t] = (a0 + a1) + (a2 + a3);
    if (t < 256) Wt[(size_t)c1 * D_ + t] = __float2bfloat16(W[(size_t)t * DC + c1]);
    __syncthreads();
    if (h == 0)
        G[c1 * DC + c2] =
            __float2bfloat16(red[c2] + red[128 + c2] + red[256 + c2] + red[384 + c2]);
}

// ---------------------------------------------------------------------------
// qproj body: q_proj = (q @ W_up) -> bf16, q_sq fused. 256 blocks x 32 rows.
static __device__ __forceinline__ void qproj_body(
        char* smem, int blk,
        const float* __restrict__ q, const __hip_bfloat16* __restrict__ Wt,
        __hip_bfloat16* __restrict__ qproj, float* __restrict__ q_sq) {
    __hip_bfloat16* sA = (__hip_bfloat16*)smem;          // [32][72]
    __hip_bfloat16* sB = sA + 32 * 72;                   // [128][72]
    int t = threadIdx.x, lane = t & 63, w = t >> 6;
    int quad = lane >> 4, li = lane & 15;
    int wm = w >> 1, wn = w & 1;
    int row0 = blk * 32;

    float psum[2] = {0.f, 0.f};
    floatx4 acc[4];
#pragma unroll
    for (int nt = 0; nt < 4; ++nt) acc[nt] = (floatx4){0.f, 0.f, 0.f, 0.f};

    for (int kc4 = 0; kc4 < 4; ++kc4) {
#pragma unroll
        for (int it = 0; it < 2; ++it) {
            int idx = it * 256 + t;
            int r = idx >> 4, pos = idx & 15;
            float4 v = *(const float4*)(q + (size_t)(row0 + r) * D_ + kc4 * 64 + pos * 4);
            psum[it] += v.x * v.x + v.y * v.y + v.z * v.z + v.w * v.w;
            __hip_bfloat16* dst = &sA[r * 72 + pos * 4];
            dst[0] = __float2bfloat16(v.x); dst[1] = __float2bfloat16(v.y);
            dst[2] = __float2bfloat16(v.z); dst[3] = __float2bfloat16(v.w);
        }
#pragma unroll
        for (int it = 0; it < 4; ++it) {
            int e = it * 256 + t;          // [0,1024): 128 rows x 8 chunks
            int c = e >> 3, ch = e & 7;
            *(uint4*)&sB[c * 72 + ch * 8] =
                *(const uint4*)(Wt + (size_t)c * D_ + kc4 * 64 + ch * 8);
        }
        __syncthreads();
        short8 af[2];
#pragma unroll
        for (int ks = 0; ks < 2; ++ks)
            af[ks] = *(const short8*)&sA[(wm * 16 + li) * 72 + ks * 32 + quad * 8];
#pragma unroll
        for (int nt = 0; nt < 4; ++nt)
#pragma unroll
            for (int ks = 0; ks < 2; ++ks) {
                short8 bf = *(const short8*)&sB[((wn * 4 + nt) * 16 + li) * 72 + ks * 32 + quad * 8];
                acc[nt] = mfma16(af[ks], bf, acc[nt]);
            }
        __syncthreads();
    }
#pragma unroll
    for (int nt = 0; nt < 4; ++nt)
#pragma unroll
        for (int r = 0; r < 4; ++r) {
            int row = wm * 16 + quad * 4 + r;
            qproj[(size_t)(row0 + row) * DC + (wn * 4 + nt) * 16 + li] =
                __float2bfloat16(acc[nt][r]);
        }
#pragma unroll
    for (int it = 0; it < 2; ++it) {
        float s = psum[it];
        s += __shfl_xor(s, 1); s += __shfl_xor(s, 2);
        s += __shfl_xor(s, 4); s += __shfl_xor(s, 8);
        if (li == 0) q_sq[row0 + it * 16 + w * 4 + quad] = s;
    }
}

// ---------------------------------------------------------------------------
// dq_ksq body: dequant 64 rows -> kc (global) + LDS; k_sq via MFMA row-dot.
static __device__ __forceinline__ void dq_body(
        char* smem, int blk,
        const int* __restrict__ kq, const float* __restrict__ kscale,
        const float* __restrict__ kzero, const __hip_bfloat16* __restrict__ G,
        __hip_bfloat16* __restrict__ kc, float* __restrict__ k_sq) {
    __hip_bfloat16* sK = (__hip_bfloat16*)smem;          // [64][132]
    int t = threadIdx.x, lane = t & 63, w = t >> 6;
    int quad = lane >> 4, li = lane & 15;
    int b = blk >> 7, l0 = (blk & 127) * 64;

    const int4* codes = (const int4*)(kq + ((size_t)b * LK + l0) * DC);
    int col = (t & 31) * 4;
    float4 sc = *(const float4*)(kscale + b * DC + col);
    float4 zp = *(const float4*)(kzero + b * DC + col);
    __hip_bfloat16* kco = kc + ((size_t)b * LK + l0) * DC;
#pragma unroll
    for (int it = 0; it < 8; ++it) {
        int idx = it * 256 + t;            // [0,2048)
        int r = idx >> 5;
        int4 c4 = codes[idx];
        __hip_bfloat16 tmp[4];
        tmp[0] = __float2bfloat16(sc.x * ((float)c4.x - zp.x));
        tmp[1] = __float2bfloat16(sc.y * ((float)c4.y - zp.y));
        tmp[2] = __float2bfloat16(sc.z * ((float)c4.z - zp.z));
        tmp[3] = __float2bfloat16(sc.w * ((float)c4.w - zp.w));
        *(uint2*)&sK[r * 132 + col] = *(const uint2*)tmp;
        *(uint2*)(kco + idx * 4)    = *(const uint2*)tmp;
    }
    __syncthreads();

    short8 af[4];
#pragma unroll
    for (int ks = 0; ks < 4; ++ks)
        af[ks] = *(const short8*)&sK[(w * 16 + li) * 132 + ks * 32 + quad * 8];
    float s4[4] = {0.f, 0.f, 0.f, 0.f};
#pragma unroll
    for (int nt = 0; nt < 8; ++nt) {
        floatx4 a0 = (floatx4){0.f, 0.f, 0.f, 0.f};
#pragma unroll
        for (int ks = 0; ks < 4; ++ks) {
            short8 bf = *(const short8*)(G + (size_t)(nt * 16 + li) * DC + ks * 32 + quad * 8);
            a0 = mfma16(af[ks], bf, a0);
        }
        int c2 = nt * 16 + li;
#pragma unroll
        for (int r = 0; r < 4; ++r)
            s4[r] += a0[r] * __bfloat162float(sK[(w * 16 + quad * 4 + r) * 132 + c2]);
    }
#pragma unroll
    for (int r = 0; r < 4; ++r) {
        float v = s4[r];
        v += __shfl_xor(v, 1); v += __shfl_xor(v, 2);
        v += __shfl_xor(v, 4); v += __shfl_xor(v, 8);
        if (li == 0)
            k_sq[(size_t)b * LK + l0 + w * 16 + quad * 4 + r] = v;
    }
}

// ---------------------------------------------------------------------------
// K2 fused prep: blocks [0,256) run qproj, [256,1280) run dq_ksq — both
// depend only on k_G, so they share one launch and co-schedule (latency-bound
// qproj + BW-bound dq are good co-residents). One launch gap removed.
__global__ __launch_bounds__(256) void k_prep(const float* __restrict__ q,
                                              const __hip_bfloat16* __restrict__ Wt,
                                              __hip_bfloat16* __restrict__ qproj,
                                              float* __restrict__ q_sq,
                                              const int* __restrict__ kq,
                                              const float* __restrict__ kscale,
                                              const float* __restrict__ kzero,
                                              const __hip_bfloat16* __restrict__ G,
                                              __hip_bfloat16* __restrict__ kc,
                                              float* __restrict__ k_sq) {
    __shared__ __align__(16) char smem[23040];   // max(qproj 23040, dq 16896)
    if (blockIdx.x < 256)
        qproj_body(smem, blockIdx.x, q, Wt, qproj, q_sq);
    else
        dq_body(smem, blockIdx.x - 256, kq, kscale, kzero, G, kc, k_sq);
}

// ---------------------------------------------------------------------------
// K3: main — PERSISTENT (1024 blocks x 4 n-tiles, fixed b/m0 per block) with
// R4's gl16+swizzle core and R2's verified LDS-transpose epilogue so every
// nontemporal store covers full 128B HBM lines (4 rows x 2x128B per instr).
// Theory: nt scatter stores (64B granules) were partial-line writes at ~1.7
// TB/s effective; full-line nt stores should restore ~6.5 TB/s on the 268 MB
// output stream. sO unions over sA/sB: LDS 34.8 KB -> 4 blocks/CU kept.
__global__ __launch_bounds__(256, 4) void k_main(const __hip_bfloat16* __restrict__ qproj,
                                                 const __hip_bfloat16* __restrict__ kc,
                                                 const float* __restrict__ q_sq,
                                                 const float* __restrict__ k_sq,
                                                 float* __restrict__ out) {
    __shared__ __align__(16) char smem[34816];   // max(sA+sB 32KB, sO 34.8KB)
    __hip_bfloat16* sA = (__hip_bfloat16*)smem;  // [128][64] current k-half of qproj
    __hip_bfloat16* sB = sA + 128 * 64;          // [128][64] current k-half of kc
    float* sO = (float*)smem;                    // [128][68] epilogue transpose

    int t = threadIdx.x, lane = t & 63, w = t >> 6;
    int quad = lane >> 4, li = lane & 15;
    int wm = w >> 1, wn = w & 1;
    int blk = blockIdx.x;
    int b    = blk & 7;                // XCD-pinned batch (1024 % 8 == 0: exact)
    int rem0 = blk >> 3;               // 0..127
    int m0   = (rem0 & 7) << 7;        // fixed per block
    int nt0  = rem0 >> 3;              // 0..15 ; tiles: n0 = (nt0 + s*16)*128
    const char* Ag = (const char*)(qproj + ((size_t)b * LQ + m0) * DC);  // 256 B rows

    int lrow = lane >> 3;              // 0..7
    int lch  = (lane & 7) ^ lrow;      // pre-swizzled source chunk (16 B units)

    // epilogue thread mapping + per-block q-row terms (m0 fixed -> hoisted)
    int orow_t = t >> 4;               // 0..15
    int ocol4  = (t & 15) * 4;         // 0..60
    float qsA[8], omqA[8];
#pragma unroll
    for (int qq = 0; qq < 8; ++qq) {
        qsA[qq]  = q_sq[(size_t)b * LQ + m0 + qq * 16 + orow_t];
        omqA[qq] = 1.f - fminf(qsA[qq], 1.f - EPSF);
    }

    for (int s = 0; s < 4; ++s) {
        int n0 = (nt0 + s * 16) << 7;
        const char* Bg = (const char*)(kc + ((size_t)b * LK + n0) * DC);

        floatx4 acc[4][4];
#pragma unroll
        for (int i = 0; i < 4; ++i)
#pragma unroll
            for (int j = 0; j < 4; ++j)
                acc[i][j] = (floatx4){0.f, 0.f, 0.f, 0.f};

#pragma unroll
        for (int h = 0; h < 2; ++h) {
#pragma unroll
            for (int it = 0; it < 4; ++it) {
                int rbase = it * 32 + w * 8;                   // wave-uniform
                size_t goff = (size_t)(rbase + lrow) * 256 + (size_t)(h * 8 + lch) * 16;
                gl16(Ag + goff, (char*)sA + rbase * 128);
                gl16(Bg + goff, (char*)sB + rbase * 128);
            }
            __syncthreads();   // drains vmcnt(0) before barrier
#pragma unroll
            for (int ks = 0; ks < 2; ++ks) {
                int ac = ((ks * 4 + quad) ^ (li & 7)) * 16;    // swizzled read
                short8 qf[4], kf[4];
#pragma unroll
                for (int i = 0; i < 4; ++i) {
                    qf[i] = *(const short8*)((const char*)sA + (wm * 64 + i * 16 + li) * 128 + ac);
                    kf[i] = *(const short8*)((const char*)sB + (wn * 64 + i * 16 + li) * 128 + ac);
                }
#pragma unroll
                for (int i = 0; i < 4; ++i)
#pragma unroll
                    for (int j = 0; j < 4; ++j)
                        acc[i][j] = mfma16(kf[j], qf[i], acc[i][j]);   // A=kc, B=qproj
            }
            __syncthreads();   // LDS reads done (sA/sB reusable / sO writable)
        }

        // ---- epilogue: LDS transpose + math + full-line nt stores ----
#pragma unroll
        for (int p = 0; p < 2; ++p) {
#pragma unroll
            for (int jj = 0; jj < 2; ++jj) {
                int c = wn * 32 + jj * 16 + quad * 4;
#pragma unroll
                for (int i = 0; i < 4; ++i) {
                    int m = wm * 64 + i * 16 + li;
                    *(floatx4*)&sO[m * 68 + c] = acc[i][p * 2 + jj];
                }
            }
            __syncthreads();
            int nbase = (ocol4 >> 5) * 64 + p * 32 + (ocol4 & 31);
            floatx4 ks4 = *(const floatx4*)(k_sq + (size_t)b * LK + n0 + nbase);
            floatx4 kn;
#pragma unroll
            for (int r = 0; r < 4; ++r)
                kn[r] = 1.f - fminf(ks4[r], 1.f - EPSF);
#pragma unroll
            for (int qq = 0; qq < 8; ++qq) {
                int row = qq * 16 + orow_t;
                floatx4 v = *(const floatx4*)&sO[row * 68 + ocol4];
                float qs = qsA[qq], omq = omqA[qq];
                floatx4 o;
#pragma unroll
                for (int r = 0; r < 4; ++r) {
                    float diff  = fmaxf(qs + ks4[r] - 2.f * v[r], 0.f);
                    float delta = 2.f * diff * fast_rcp(omq * kn[r] + EPSF);
                    float sq    = fast_sqrt(delta * (delta + 2.f));
                    o[r] = fast_ln(1.f + delta + sq);
                }
                __builtin_nontemporal_store(
                    o, (floatx4*)(out + ((size_t)b * LQ + m0 + row) * (size_t)LK + n0 + nbase));
            }
            __syncthreads();   // sO reads done before next phase/tile write
        }
    }
}

// ---------------------------------------------------------------------------
extern "C" void kernel_launch(void* const* d_in, const int* in_sizes, int n_in,
                              void* d_out, int out_size, void* d_ws, size_t ws_size,
                              hipStream_t stream) {
    const float* q      = (const float*)d_in[0];
    const int*   kq     = (const int*)d_in[1];
    const float* kscale = (const float*)d_in[2];
    const float* kzero  = (const float*)d_in[3];
    const float* W      = (const float*)d_in[4];
    float* out = (float*)d_out;

    // workspace layout (19.2 MB total, unchanged)
    char* ws = (char*)d_ws;
    __hip_bfloat16* qproj = (__hip_bfloat16*)(ws);                 // 2,097,152 B
    __hip_bfloat16* kc    = (__hip_bfloat16*)(ws + 2097152);       // 16,777,216 B
    __hip_bfloat16* G     = (__hip_bfloat16*)(ws + 18874368);      //    32,768 B
    float*          q_sq  = (float*)(ws + 18907136);               //    32,768 B
    float*          k_sq  = (float*)(ws + 18939904);               //   262,144 B
    // Wt scratch = first 64 KB of OUT: k_G writes it, k_prep reads it,
    // k_main overwrites it (stream-ordered; no race with concurrent kc writes).
    __hip_bfloat16* Wt    = (__hip_bfloat16*)out;

    k_G    <<<128, 512, 0, stream>>>(W, G, Wt);
    k_prep <<<1280, 256, 0, stream>>>(q, Wt, qproj, q_sq, kq, kscale, kzero, G, kc, k_sq);
    k_main <<<1024, 256, 0, stream>>>(qproj, kc, q_sq, k_sq, out);
}